// Round 8
// baseline (47.843 us; speedup 1.0000x reference)
//
#include <hip/hip_runtime.h>
#include <math.h>

#define BB 32
#define Q 2000
#define NC 91
#define NA 18
#define K 100
#define N (Q*NC)          // 182000
#define N4 (N/4)          // 45500
#define NBINS 4096
#define G 16              // segment blocks per (b,branch)
#define BLK1 512
#define CHUNK4 ((N4 + G - 1) / G)           // 2844 float4 per phase-1 block
#define ITERS ((CHUNK4 + BLK1 - 1) / BLK1)  // 6
#define CAPSEG 512        // per-segment candidate cap
#define CAP2 1024         // finalist cap
#define SUBROWS 10        // adj rows per det sub-block

// output offsets (flat f32 concat in reference return order)
#define O_V     0        // (B,K)      3200
#define O_LAB   3200     // (B,K)      3200
#define O_BOX   6400     // (B,K,4)    12800
#define O_VG    19200    // (B,K)      3200
#define O_LABG  22400    // (B,K)      3200
#define O_BG    25600    // (B,K,5)    16000
#define O_ADJ   41600    // (B,K,K)    320000
#define O_KEEP  361600   // (B,K)      3200

__device__ __forceinline__ unsigned okey(float f) {
    unsigned u = __float_as_uint(f);
    return (u & 0x80000000u) ? ~u : (u | 0x80000000u);
}

__device__ __forceinline__ float sigm(float x) { return 1.f / (1.f + expf(-x)); }

// Block-wide EXCLUSIVE suffix sum of per-thread totals s (one barrier).
template<int NWAVES>
__device__ __forceinline__ unsigned suffix_excl(unsigned s, int tid, unsigned* wsum) {
    const int lane = tid & 63, wv = tid >> 6;
    unsigned x = s;
    #pragma unroll
    for (int off = 1; off < 64; off <<= 1) {
        unsigned y = (unsigned)__shfl_down((int)x, off, 64);
        if (lane + off < 64) x += y;        // inclusive suffix within wave
    }
    if (lane == 0) wsum[wv] = x;            // wave total
    __syncthreads();
    unsigned acc = 0;
    #pragma unroll
    for (int w = 0; w < NWAVES; ++w) if (w > wv) acc += wsum[w];
    return (x - s) + acc;
}

// ---------------- K1: segmented candidate generation (unchanged, proven) ----------------
__global__ __launch_bounds__(BLK1) void topk_part(const float* __restrict__ logits,
                                                  const float* __restrict__ logits_g,
                                                  unsigned* __restrict__ cnt2,
                                                  float* __restrict__ gv,
                                                  int* __restrict__ gi) {
    const int g  = blockIdx.x;           // 0..G-1
    const int bw = blockIdx.y;           // 0..63: b = bw>>1, which = bw&1
    const int b = bw >> 1, which = bw & 1;
    const float4* s4 = (const float4*)((which ? logits_g : logits) + (size_t)b * N);
    const int i0 = g * CHUNK4;
    const int i1 = (i0 + CHUNK4 < N4) ? (i0 + CHUNK4) : N4;

    __shared__ unsigned hist[NBINS];
    __shared__ unsigned wsum[BLK1 / 64];
    __shared__ int s_thr;
    __shared__ unsigned s_cnt;

    const int tid = threadIdx.x;
    for (int i = tid; i < NBINS; i += BLK1) hist[i] = 0u;
    if (tid == 0) s_cnt = 0u;
    __syncthreads();

    // pass A: histogram + per-thread max key per iteration
    unsigned mk[ITERS];
    #pragma unroll
    for (int t = 0; t < ITERS; ++t) {
        const int i = i0 + tid + t * BLK1;
        unsigned m = 0u;
        if (i < i1) {
            float4 v = s4[i];
            const unsigned k0 = okey(v.x) >> 20;
            const unsigned k1 = okey(v.y) >> 20;
            const unsigned k2 = okey(v.z) >> 20;
            const unsigned k3 = okey(v.w) >> 20;
            atomicAdd(&hist[k0], 1u);
            atomicAdd(&hist[k1], 1u);
            atomicAdd(&hist[k2], 1u);
            atomicAdd(&hist[k3], 1u);
            const unsigned m01 = k0 > k1 ? k0 : k1;
            const unsigned m23 = k2 > k3 ? k2 : k3;
            m = m01 > m23 ? m01 : m23;
        }
        mk[t] = m;
    }
    __syncthreads();

    // local top-K threshold bin (1-barrier wave suffix scan)
    {
        unsigned h[8];
        unsigned s = 0;
        #pragma unroll
        for (int k = 0; k < 8; ++k) { h[k] = hist[tid * 8 + k]; s += h[k]; }
        unsigned sfx = suffix_excl<BLK1 / 64>(s, tid, wsum);
        #pragma unroll
        for (int k = 7; k >= 0; --k) {
            unsigned nxt = sfx;
            sfx += h[k];
            if (sfx >= (unsigned)K && nxt < (unsigned)K) s_thr = tid * 8 + k;
        }
    }
    __syncthreads();

    // pass B: thread-granular skip re-read
    const unsigned thr = (unsigned)s_thr;
    const size_t base = (size_t)(bw * G + g) * CAPSEG;
    #pragma unroll
    for (int t = 0; t < ITERS; ++t) {
        if (mk[t] >= thr) {
            const int i = i0 + tid + t * BLK1;
            float4 v = s4[i];
            float xs[4] = {v.x, v.y, v.z, v.w};
            #pragma unroll
            for (int u = 0; u < 4; ++u) {
                if ((okey(xs[u]) >> 20) >= thr) {
                    unsigned p = atomicAdd(&s_cnt, 1u);
                    if (p < (unsigned)CAPSEG) { gv[base + p] = xs[u]; gi[base + p] = i * 4 + u; }
                }
            }
        }
    }
    __syncthreads();
    if (tid == 0) {
        unsigned c = s_cnt;
        cnt2[bw * G + g] = (c < (unsigned)CAPSEG) ? c : (unsigned)CAPSEG;
    }
}

// Re-derive the exact top-K for one (b,branch) from the candidate regions.
// Deterministic regardless of atomic collection order (rank-based placement).
// Results land in ovv/ovi. Uses hist/wsum/sv/si LDS scratch.
__device__ __forceinline__ void merge_bw(int bw,
                                         const unsigned* __restrict__ cnt2,
                                         const float* __restrict__ gv,
                                         const int* __restrict__ gi,
                                         unsigned* hist, unsigned* wsum,
                                         float* sv, int* si,
                                         float* ovv, int* ovi,
                                         int* p_thr, unsigned* p_cnt,
                                         unsigned* segc) {
    const int tid = threadIdx.x;
    for (int i = tid; i < NBINS; i += BLK1) hist[i] = 0u;
    if (tid == 0) *p_cnt = 0u;
    if (tid < G) segc[tid] = cnt2[bw * G + tid];
    __syncthreads();

    // histogram all candidates (global reads, L2-hot)
    for (int g2 = 0; g2 < G; ++g2) {
        const int c = (int)segc[g2];
        const size_t bs2 = (size_t)(bw * G + g2) * CAPSEG;
        for (int i = tid; i < c; i += BLK1)
            atomicAdd(&hist[okey(gv[bs2 + i]) >> 20], 1u);
    }
    __syncthreads();

    // top-K threshold bin
    {
        unsigned h[8];
        unsigned s = 0;
        #pragma unroll
        for (int k = 0; k < 8; ++k) { h[k] = hist[tid * 8 + k]; s += h[k]; }
        unsigned sfx = suffix_excl<BLK1 / 64>(s, tid, wsum);
        #pragma unroll
        for (int k = 7; k >= 0; --k) {
            unsigned nxt = sfx;
            sfx += h[k];
            if (sfx >= (unsigned)K && nxt < (unsigned)K) *p_thr = tid * 8 + k;
        }
    }
    __syncthreads();

    // collect finalists
    {
        const unsigned thr = (unsigned)*p_thr;
        for (int g2 = 0; g2 < G; ++g2) {
            const int c = (int)segc[g2];
            const size_t bs2 = (size_t)(bw * G + g2) * CAPSEG;
            for (int i = tid; i < c; i += BLK1) {
                float x = gv[bs2 + i];
                if ((okey(x) >> 20) >= thr) {
                    unsigned p = atomicAdd(p_cnt, 1u);
                    if (p < (unsigned)CAP2) { sv[p] = x; si[p] = gi[bs2 + i]; }
                }
            }
        }
    }
    __syncthreads();

    // exact rank (desc value, asc index)
    const int c2 = (int)((*p_cnt < (unsigned)CAP2) ? *p_cnt : (unsigned)CAP2);
    for (int i = tid; i < c2; i += BLK1) {
        const float vi = sv[i];
        const int ii = si[i];
        int r = 0;
        for (int j = 0; j < c2; ++j) {
            const float vj = sv[j];
            r += (vj > vi || (vj == vi && si[j] < ii)) ? 1 : 0;
        }
        if (r < K) { ovv[r] = vi; ovi[r] = ii; }
    }
    __syncthreads();
}

// ---------------- K2: redundant merge + finalize + adj (no cross-block deps) ----------------
// grid (SUBROWS+1, BB); block 512.
//   sub 0..9 : merge det branch (redundant x10), sub==0 finalizes det, each does 10 adj rows.
//   sub 10   : merge grasp branch, finalize grasp.
__global__ __launch_bounds__(BLK1) void merge_adj(const unsigned* __restrict__ cnt2,
                                                  const float* __restrict__ gv,
                                                  const int* __restrict__ gi,
                                                  const float* __restrict__ boxes_in,
                                                  const float* __restrict__ boxes_g_in,
                                                  const float* __restrict__ angles_in,
                                                  const float* __restrict__ adj_in,
                                                  const float* __restrict__ tsz,
                                                  float* __restrict__ out) {
    const int sub = blockIdx.x;          // 0..SUBROWS
    const int b   = blockIdx.y;          // 0..31

    __shared__ unsigned hist[NBINS];     // 16 KB
    __shared__ unsigned wsum[BLK1 / 64];
    __shared__ unsigned segc[G];
    __shared__ float sv[CAP2];           // 4 KB
    __shared__ int   si[CAP2];           // 4 KB
    __shared__ float ovv[K];
    __shared__ int   ovi[K];
    __shared__ int   qArr[K];
    __shared__ int   keepArr[K];
    __shared__ int s_thr;
    __shared__ unsigned s_cnt;

    const int tid = threadIdx.x;
    const float Himg = tsz[b * 2 + 0];
    const float Wimg = tsz[b * 2 + 1];

    if (sub < SUBROWS) {
        // ---- det branch ----
        merge_bw(2 * b, cnt2, gv, gi, hist, wsum, sv, si, ovv, ovi, &s_thr, &s_cnt, segc);

        if (tid < K) {
            const int idx = ovi[tid];
            const float sp = sigm(ovv[tid]);
            qArr[tid] = idx / NC;
            keepArr[tid] = (sp > 0.3f) ? 1 : 0;
        }
        __syncthreads();

        if (sub == 0 && tid < K) {
            const float sp = sigm(ovv[tid]);
            const int idx = ovi[tid];
            const int q = qArr[tid];
            const int lab = idx - q * NC;
            const int keep = keepArr[tid];
            out[O_V + b * K + tid] = sp;
            out[O_LAB + b * K + tid] = keep ? (float)lab : -1.f;
            const float* pb = boxes_in + ((size_t)b * Q + q) * 4;
            const float cx = pb[0], cy = pb[1], w = pb[2], hh = pb[3];
            float* ob = out + O_BOX + ((size_t)b * K + tid) * 4;
            ob[0] = (cx - 0.5f * w) * Wimg;
            ob[1] = (cy - 0.5f * hh) * Himg;
            ob[2] = (cx + 0.5f * w) * Wimg;
            ob[3] = (cy + 0.5f * hh) * Himg;
            out[O_KEEP + b * K + tid] = keep ? 1.f : 0.f;
        }

        // ---- adj rows [sub*10, sub*10+10) ----
        for (int e = tid; e < SUBROWS * K; e += BLK1) {
            const int i = sub * SUBROWS + e / K;
            const int j = e - (e / K) * K;
            const int qi = qArr[i];
            const int qj = qArr[j];
            float val = 0.f;
            if (keepArr[i] & keepArr[j]) {
                val = sigm(adj_in[((size_t)b * Q + qi) * Q + qj]);
            }
            out[O_ADJ + ((size_t)b * K + i) * K + j] = val;
        }
    } else {
        // ---- grasp branch ----
        merge_bw(2 * b + 1, cnt2, gv, gi, hist, wsum, sv, si, ovv, ovi, &s_thr, &s_cnt, segc);

        if (tid < K) {
            const float sp = sigm(ovv[tid]);
            const int idx = ovi[tid];
            const int q = idx / NC;
            const int lab = idx - q * NC;
            out[O_VG + b * K + tid] = sp;
            out[O_LABG + b * K + tid] = (float)lab;
            const float* pg = boxes_g_in + ((size_t)b * Q + q) * 4;
            float* obg = out + O_BG + ((size_t)b * K + tid) * 5;
            obg[0] = pg[0] * Wimg;
            obg[1] = pg[1] * Himg;
            obg[2] = pg[2] * Wimg;
            obg[3] = pg[3] * Himg;
            const float* pa = angles_in + ((size_t)b * Q + q) * NA;
            int am = 0;
            float bv = pa[0];
            #pragma unroll
            for (int a = 1; a < NA; ++a) {
                const float x = pa[a];
                if (x > bv) { bv = x; am = a; }
            }
            obg[4] = (float)((am - 8) * 10 - 5);
        }
    }
}

extern "C" void kernel_launch(void* const* d_in, const int* in_sizes, int n_in,
                              void* d_out, int out_size, void* d_ws, size_t ws_size,
                              hipStream_t stream) {
    const float* pred_logits   = (const float*)d_in[0];
    const float* pred_boxes    = (const float*)d_in[1];
    const float* pred_adj      = (const float*)d_in[2];
    const float* pred_logits_g = (const float*)d_in[3];
    const float* pred_angles_g = (const float*)d_in[4];
    const float* pred_boxes_g  = (const float*)d_in[5];
    const float* tsz           = (const float*)d_in[6];
    float* out = (float*)d_out;

    // ws layout (4B units): cnt2[64*G] | gv[64*G*CAPSEG] | gi[64*G*CAPSEG]
    unsigned* cnt2 = (unsigned*)d_ws;
    float* gv = (float*)(cnt2 + 64 * G);
    int*   gi = (int*)(gv + (size_t)64 * G * CAPSEG);

    hipLaunchKernelGGL(topk_part, dim3(G, 64), dim3(BLK1), 0, stream,
                       pred_logits, pred_logits_g, cnt2, gv, gi);
    hipLaunchKernelGGL(merge_adj, dim3(SUBROWS + 1, BB), dim3(BLK1), 0, stream,
                       cnt2, gv, gi, pred_boxes, pred_boxes_g, pred_angles_g,
                       pred_adj, tsz, out);
}

// Round 9
// 44.781 us; speedup vs baseline: 1.0684x; 1.0684x over previous
//
#include <hip/hip_runtime.h>
#include <math.h>

#define BB 32
#define Q 2000
#define NC 91
#define NA 18
#define K 100
#define N (Q*NC)          // 182000
#define N4 (N/4)          // 45500
#define NBINS 4096
#define G 16              // segment blocks per (b,branch)
#define BLK1 512
#define CHUNK4 ((N4 + G - 1) / G)           // 2844 float4 per phase-1 block
#define ITERS ((CHUNK4 + BLK1 - 1) / BLK1)  // 6
#define CAPSEG 512        // per-segment candidate cap (power of 2!)
#define CAPSEG_SH 9
#define CAP2 1024         // finalist cap
#define SUBROWS 10        // adj rows per det sub-block

// output offsets (flat f32 concat in reference return order)
#define O_V     0        // (B,K)      3200
#define O_LAB   3200     // (B,K)      3200
#define O_BOX   6400     // (B,K,4)    12800
#define O_VG    19200    // (B,K)      3200
#define O_LABG  22400    // (B,K)      3200
#define O_BG    25600    // (B,K,5)    16000
#define O_ADJ   41600    // (B,K,K)    320000
#define O_KEEP  361600   // (B,K)      3200

__device__ __forceinline__ unsigned okey(float f) {
    unsigned u = __float_as_uint(f);
    return (u & 0x80000000u) ? ~u : (u | 0x80000000u);
}

__device__ __forceinline__ float sigm(float x) { return 1.f / (1.f + expf(-x)); }

// Block-wide EXCLUSIVE suffix sum of per-thread totals s (one barrier).
template<int NWAVES>
__device__ __forceinline__ unsigned suffix_excl(unsigned s, int tid, unsigned* wsum) {
    const int lane = tid & 63, wv = tid >> 6;
    unsigned x = s;
    #pragma unroll
    for (int off = 1; off < 64; off <<= 1) {
        unsigned y = (unsigned)__shfl_down((int)x, off, 64);
        if (lane + off < 64) x += y;        // inclusive suffix within wave
    }
    if (lane == 0) wsum[wv] = x;            // wave total
    __syncthreads();
    unsigned acc = 0;
    #pragma unroll
    for (int w = 0; w < NWAVES; ++w) if (w > wv) acc += wsum[w];
    return (x - s) + acc;
}

// ---------------- K1: segmented candidate generation (unchanged, proven) ----------------
__global__ __launch_bounds__(BLK1) void topk_part(const float* __restrict__ logits,
                                                  const float* __restrict__ logits_g,
                                                  unsigned* __restrict__ cnt2,
                                                  float* __restrict__ gv,
                                                  int* __restrict__ gi) {
    const int g  = blockIdx.x;           // 0..G-1
    const int bw = blockIdx.y;           // 0..63: b = bw>>1, which = bw&1
    const int b = bw >> 1, which = bw & 1;
    const float4* s4 = (const float4*)((which ? logits_g : logits) + (size_t)b * N);
    const int i0 = g * CHUNK4;
    const int i1 = (i0 + CHUNK4 < N4) ? (i0 + CHUNK4) : N4;

    __shared__ unsigned hist[NBINS];
    __shared__ unsigned wsum[BLK1 / 64];
    __shared__ int s_thr;
    __shared__ unsigned s_cnt;

    const int tid = threadIdx.x;
    for (int i = tid; i < NBINS; i += BLK1) hist[i] = 0u;
    if (tid == 0) s_cnt = 0u;
    __syncthreads();

    // pass A: histogram + per-thread max key per iteration
    unsigned mk[ITERS];
    #pragma unroll
    for (int t = 0; t < ITERS; ++t) {
        const int i = i0 + tid + t * BLK1;
        unsigned m = 0u;
        if (i < i1) {
            float4 v = s4[i];
            const unsigned k0 = okey(v.x) >> 20;
            const unsigned k1 = okey(v.y) >> 20;
            const unsigned k2 = okey(v.z) >> 20;
            const unsigned k3 = okey(v.w) >> 20;
            atomicAdd(&hist[k0], 1u);
            atomicAdd(&hist[k1], 1u);
            atomicAdd(&hist[k2], 1u);
            atomicAdd(&hist[k3], 1u);
            const unsigned m01 = k0 > k1 ? k0 : k1;
            const unsigned m23 = k2 > k3 ? k2 : k3;
            m = m01 > m23 ? m01 : m23;
        }
        mk[t] = m;
    }
    __syncthreads();

    // local top-K threshold bin (1-barrier wave suffix scan)
    {
        unsigned h[8];
        unsigned s = 0;
        #pragma unroll
        for (int k = 0; k < 8; ++k) { h[k] = hist[tid * 8 + k]; s += h[k]; }
        unsigned sfx = suffix_excl<BLK1 / 64>(s, tid, wsum);
        #pragma unroll
        for (int k = 7; k >= 0; --k) {
            unsigned nxt = sfx;
            sfx += h[k];
            if (sfx >= (unsigned)K && nxt < (unsigned)K) s_thr = tid * 8 + k;
        }
    }
    __syncthreads();

    // pass B: thread-granular skip re-read
    const unsigned thr = (unsigned)s_thr;
    const size_t base = (size_t)(bw * G + g) * CAPSEG;
    #pragma unroll
    for (int t = 0; t < ITERS; ++t) {
        if (mk[t] >= thr) {
            const int i = i0 + tid + t * BLK1;
            float4 v = s4[i];
            float xs[4] = {v.x, v.y, v.z, v.w};
            #pragma unroll
            for (int u = 0; u < 4; ++u) {
                if ((okey(xs[u]) >> 20) >= thr) {
                    unsigned p = atomicAdd(&s_cnt, 1u);
                    if (p < (unsigned)CAPSEG) { gv[base + p] = xs[u]; gi[base + p] = i * 4 + u; }
                }
            }
        }
    }
    __syncthreads();
    if (tid == 0) {
        unsigned c = s_cnt;
        cnt2[bw * G + g] = (c < (unsigned)CAPSEG) ? c : (unsigned)CAPSEG;
    }
}

// Re-derive the exact top-K for one (b,branch). FLATTENED slot loops: the whole
// G*CAPSEG slot space is strided by all threads with predicated loads, so the
// per-segment global reads issue concurrently (no latency chaining).
// Rank-based placement => deterministic regardless of collection order.
__device__ __forceinline__ void merge_bw(int bw,
                                         const unsigned* __restrict__ cnt2,
                                         const float* __restrict__ gv,
                                         const int* __restrict__ gi,
                                         unsigned* hist, unsigned* wsum,
                                         float* sv, int* si,
                                         float* ovv, int* ovi,
                                         int* p_thr, unsigned* p_cnt,
                                         unsigned* segc) {
    const int tid = threadIdx.x;
    for (int i = tid; i < NBINS; i += BLK1) hist[i] = 0u;
    if (tid == 0) *p_cnt = 0u;
    if (tid < G) segc[tid] = cnt2[bw * G + tid];
    __syncthreads();

    const size_t rbase = (size_t)bw * G * CAPSEG;

    // histogram all candidates — flattened over slots
    #pragma unroll
    for (int t = 0; t < (G * CAPSEG) / BLK1; ++t) {
        const int slot = tid + t * BLK1;
        const int g2 = slot >> CAPSEG_SH;
        const int off = slot & (CAPSEG - 1);
        if ((unsigned)off < segc[g2])
            atomicAdd(&hist[okey(gv[rbase + slot]) >> 20], 1u);
    }
    __syncthreads();

    // top-K threshold bin
    {
        unsigned h[8];
        unsigned s = 0;
        #pragma unroll
        for (int k = 0; k < 8; ++k) { h[k] = hist[tid * 8 + k]; s += h[k]; }
        unsigned sfx = suffix_excl<BLK1 / 64>(s, tid, wsum);
        #pragma unroll
        for (int k = 7; k >= 0; --k) {
            unsigned nxt = sfx;
            sfx += h[k];
            if (sfx >= (unsigned)K && nxt < (unsigned)K) *p_thr = tid * 8 + k;
        }
    }
    __syncthreads();

    // collect finalists — flattened over slots
    {
        const unsigned thr = (unsigned)*p_thr;
        #pragma unroll
        for (int t = 0; t < (G * CAPSEG) / BLK1; ++t) {
            const int slot = tid + t * BLK1;
            const int g2 = slot >> CAPSEG_SH;
            const int off = slot & (CAPSEG - 1);
            if ((unsigned)off < segc[g2]) {
                float x = gv[rbase + slot];
                if ((okey(x) >> 20) >= thr) {
                    unsigned p = atomicAdd(p_cnt, 1u);
                    if (p < (unsigned)CAP2) { sv[p] = x; si[p] = gi[rbase + slot]; }
                }
            }
        }
    }
    __syncthreads();

    // exact rank (desc value, asc index)
    const int c2 = (int)((*p_cnt < (unsigned)CAP2) ? *p_cnt : (unsigned)CAP2);
    for (int i = tid; i < c2; i += BLK1) {
        const float vi = sv[i];
        const int ii = si[i];
        int r = 0;
        for (int j = 0; j < c2; ++j) {
            const float vj = sv[j];
            r += (vj > vi || (vj == vi && si[j] < ii)) ? 1 : 0;
        }
        if (r < K) { ovv[r] = vi; ovi[r] = ii; }
    }
    __syncthreads();
}

// ---------------- K2: redundant merge + finalize + adj (no cross-block deps) ----------------
// grid (SUBROWS+1, BB); block 512.
//   sub 0..9 : merge det branch (redundant x10), sub==0 finalizes det, each does 10 adj rows.
//   sub 10   : merge grasp branch, finalize grasp.
__global__ __launch_bounds__(BLK1) void merge_adj(const unsigned* __restrict__ cnt2,
                                                  const float* __restrict__ gv,
                                                  const int* __restrict__ gi,
                                                  const float* __restrict__ boxes_in,
                                                  const float* __restrict__ boxes_g_in,
                                                  const float* __restrict__ angles_in,
                                                  const float* __restrict__ adj_in,
                                                  const float* __restrict__ tsz,
                                                  float* __restrict__ out) {
    const int sub = blockIdx.x;          // 0..SUBROWS
    const int b   = blockIdx.y;          // 0..31

    __shared__ unsigned hist[NBINS];     // 16 KB
    __shared__ unsigned wsum[BLK1 / 64];
    __shared__ unsigned segc[G];
    __shared__ float sv[CAP2];           // 4 KB
    __shared__ int   si[CAP2];           // 4 KB
    __shared__ float ovv[K];
    __shared__ int   ovi[K];
    __shared__ int   qArr[K];
    __shared__ int   keepArr[K];
    __shared__ int s_thr;
    __shared__ unsigned s_cnt;

    const int tid = threadIdx.x;
    const float Himg = tsz[b * 2 + 0];
    const float Wimg = tsz[b * 2 + 1];

    if (sub < SUBROWS) {
        // ---- det branch ----
        merge_bw(2 * b, cnt2, gv, gi, hist, wsum, sv, si, ovv, ovi, &s_thr, &s_cnt, segc);

        if (tid < K) {
            const int idx = ovi[tid];
            const float sp = sigm(ovv[tid]);
            qArr[tid] = idx / NC;
            keepArr[tid] = (sp > 0.3f) ? 1 : 0;
        }
        __syncthreads();

        if (sub == 0 && tid < K) {
            const float sp = sigm(ovv[tid]);
            const int idx = ovi[tid];
            const int q = qArr[tid];
            const int lab = idx - q * NC;
            const int keep = keepArr[tid];
            out[O_V + b * K + tid] = sp;
            out[O_LAB + b * K + tid] = keep ? (float)lab : -1.f;
            const float* pb = boxes_in + ((size_t)b * Q + q) * 4;
            const float cx = pb[0], cy = pb[1], w = pb[2], hh = pb[3];
            float* ob = out + O_BOX + ((size_t)b * K + tid) * 4;
            ob[0] = (cx - 0.5f * w) * Wimg;
            ob[1] = (cy - 0.5f * hh) * Himg;
            ob[2] = (cx + 0.5f * w) * Wimg;
            ob[3] = (cy + 0.5f * hh) * Himg;
            out[O_KEEP + b * K + tid] = keep ? 1.f : 0.f;
        }

        // ---- adj rows [sub*10, sub*10+10) ----
        for (int e = tid; e < SUBROWS * K; e += BLK1) {
            const int i = sub * SUBROWS + e / K;
            const int j = e - (e / K) * K;
            const int qi = qArr[i];
            const int qj = qArr[j];
            float val = 0.f;
            if (keepArr[i] & keepArr[j]) {
                val = sigm(adj_in[((size_t)b * Q + qi) * Q + qj]);
            }
            out[O_ADJ + ((size_t)b * K + i) * K + j] = val;
        }
    } else {
        // ---- grasp branch ----
        merge_bw(2 * b + 1, cnt2, gv, gi, hist, wsum, sv, si, ovv, ovi, &s_thr, &s_cnt, segc);

        if (tid < K) {
            const float sp = sigm(ovv[tid]);
            const int idx = ovi[tid];
            const int q = idx / NC;
            const int lab = idx - q * NC;
            out[O_VG + b * K + tid] = sp;
            out[O_LABG + b * K + tid] = (float)lab;
            const float* pg = boxes_g_in + ((size_t)b * Q + q) * 4;
            float* obg = out + O_BG + ((size_t)b * K + tid) * 5;
            obg[0] = pg[0] * Wimg;
            obg[1] = pg[1] * Himg;
            obg[2] = pg[2] * Wimg;
            obg[3] = pg[3] * Himg;
            const float* pa = angles_in + ((size_t)b * Q + q) * NA;
            int am = 0;
            float bv = pa[0];
            #pragma unroll
            for (int a = 1; a < NA; ++a) {
                const float x = pa[a];
                if (x > bv) { bv = x; am = a; }
            }
            obg[4] = (float)((am - 8) * 10 - 5);
        }
    }
}

extern "C" void kernel_launch(void* const* d_in, const int* in_sizes, int n_in,
                              void* d_out, int out_size, void* d_ws, size_t ws_size,
                              hipStream_t stream) {
    const float* pred_logits   = (const float*)d_in[0];
    const float* pred_boxes    = (const float*)d_in[1];
    const float* pred_adj      = (const float*)d_in[2];
    const float* pred_logits_g = (const float*)d_in[3];
    const float* pred_angles_g = (const float*)d_in[4];
    const float* pred_boxes_g  = (const float*)d_in[5];
    const float* tsz           = (const float*)d_in[6];
    float* out = (float*)d_out;

    // ws layout (4B units): cnt2[64*G] | gv[64*G*CAPSEG] | gi[64*G*CAPSEG]
    unsigned* cnt2 = (unsigned*)d_ws;
    float* gv = (float*)(cnt2 + 64 * G);
    int*   gi = (int*)(gv + (size_t)64 * G * CAPSEG);

    hipLaunchKernelGGL(topk_part, dim3(G, 64), dim3(BLK1), 0, stream,
                       pred_logits, pred_logits_g, cnt2, gv, gi);
    hipLaunchKernelGGL(merge_adj, dim3(SUBROWS + 1, BB), dim3(BLK1), 0, stream,
                       cnt2, gv, gi, pred_boxes, pred_boxes_g, pred_angles_g,
                       pred_adj, tsz, out);
}

// Round 10
// 41.580 us; speedup vs baseline: 1.1506x; 1.0770x over previous
//
#include <hip/hip_runtime.h>
#include <math.h>

#define BB 32
#define Q 2000
#define NC 91
#define NA 18
#define K 100
#define N (Q*NC)          // 182000
#define N4 (N/4)          // 45500
#define NBINS 4096
#define G 8               // segment blocks per (b,branch)
#define BLK1 512
#define CHUNK4 ((N4 + G - 1) / G)   // 5688 float4 per phase-1 block
#define CAPM 4096         // merge LDS candidate cap
#define CAP2 1024         // merge finalist cap

// output offsets (flat f32 concat in reference return order)
#define O_V     0        // (B,K)      3200
#define O_LAB   3200     // (B,K)      3200
#define O_BOX   6400     // (B,K,4)    12800
#define O_VG    19200    // (B,K)      3200
#define O_LABG  22400    // (B,K)      3200
#define O_BG    25600    // (B,K,5)    16000
#define O_ADJ   41600    // (B,K,K)    320000
#define O_KEEP  361600   // (B,K)      3200

__device__ __forceinline__ unsigned okey(float f) {
    unsigned u = __float_as_uint(f);
    return (u & 0x80000000u) ? ~u : (u | 0x80000000u);
}

__device__ __forceinline__ float sigm(float x) { return 1.f / (1.f + expf(-x)); }

// ---------------- Phase 1: segmented candidate generation ----------------
// grid (G, 64); block 512. Two passes over a private 91KB chunk (2nd pass L2-hot):
// pass A builds 4096-bin LDS histogram; suffix-scan finds local top-K threshold
// bin; pass B emits candidates >= threshold into this block's PRIVATE region.
// No global atomics anywhere.
__global__ __launch_bounds__(BLK1) void topk_part(const float* __restrict__ logits,
                                                  const float* __restrict__ logits_g,
                                                  unsigned* __restrict__ cnt2,
                                                  float* __restrict__ gv,
                                                  int* __restrict__ gi,
                                                  int cap) {
    const int g  = blockIdx.x;           // 0..G-1
    const int bw = blockIdx.y;           // 0..63: b = bw>>1, which = bw&1
    const int b = bw >> 1, which = bw & 1;
    const float4* s4 = (const float4*)((which ? logits_g : logits) + (size_t)b * N);
    const int i0 = g * CHUNK4;
    const int i1 = (i0 + CHUNK4 < N4) ? (i0 + CHUNK4) : N4;

    __shared__ unsigned hist[NBINS];
    __shared__ unsigned tsum[BLK1];
    __shared__ int s_thr;
    __shared__ unsigned s_cnt;

    const int tid = threadIdx.x;
    for (int i = tid; i < NBINS; i += BLK1) hist[i] = 0u;
    if (tid == 0) s_cnt = 0u;
    __syncthreads();

    // pass A: histogram
    for (int i = i0 + tid; i < i1; i += BLK1) {
        float4 v = s4[i];
        atomicAdd(&hist[okey(v.x) >> 20], 1u);
        atomicAdd(&hist[okey(v.y) >> 20], 1u);
        atomicAdd(&hist[okey(v.z) >> 20], 1u);
        atomicAdd(&hist[okey(v.w) >> 20], 1u);
    }
    __syncthreads();

    // suffix scan: 8 bins per thread
    unsigned h[8];
    unsigned s = 0;
    #pragma unroll
    for (int k = 0; k < 8; ++k) { h[k] = hist[tid * 8 + k]; s += h[k]; }
    tsum[tid] = s;
    __syncthreads();
    for (int off = 1; off < BLK1; off <<= 1) {
        unsigned add = (tid + off < BLK1) ? tsum[tid + off] : 0u;
        __syncthreads();
        tsum[tid] += add;
        __syncthreads();
    }
    unsigned sfx = (tid == BLK1 - 1) ? 0u : tsum[tid + 1];
    #pragma unroll
    for (int k = 7; k >= 0; --k) {
        unsigned nxt = sfx;
        sfx += h[k];
        if (sfx >= (unsigned)K && nxt < (unsigned)K) s_thr = tid * 8 + k;
    }
    __syncthreads();

    // pass B: collect into private region (chunk is L2-hot from pass A)
    const unsigned thr = (unsigned)s_thr;
    const size_t base = (size_t)(bw * G + g) * (size_t)cap;
    for (int i = i0 + tid; i < i1; i += BLK1) {
        float4 v = s4[i];
        float xs[4] = {v.x, v.y, v.z, v.w};
        #pragma unroll
        for (int u = 0; u < 4; ++u) {
            if ((okey(xs[u]) >> 20) >= thr) {
                unsigned p = atomicAdd(&s_cnt, 1u);
                if ((int)p < cap) { gv[base + p] = xs[u]; gi[base + p] = i * 4 + u; }
            }
        }
    }
    __syncthreads();
    if (tid == 0) {
        unsigned c = s_cnt;
        cnt2[bw * G + g] = (c < (unsigned)cap) ? c : (unsigned)cap;
    }
}

// ---------------- Phase 2: merge + exact rank + finalize epilogue ----------------
// one block per (b,branch), 1024 threads.
__global__ __launch_bounds__(1024) void topk_merge(const unsigned* __restrict__ cnt2,
                                                   const float* __restrict__ gv,
                                                   const int* __restrict__ gi,
                                                   const float* __restrict__ boxes_in,
                                                   const float* __restrict__ boxes_g_in,
                                                   const float* __restrict__ angles_in,
                                                   const float* __restrict__ tsz,
                                                   float* __restrict__ out,
                                                   int* __restrict__ ws_keep,
                                                   int* __restrict__ ws_q,
                                                   int cap) {
    const int bw = blockIdx.x;
    const int b = bw >> 1, which = bw & 1;

    __shared__ float cv[CAPM];
    __shared__ int   ci[CAPM];
    __shared__ unsigned hist[NBINS];
    __shared__ unsigned tsum[1024];
    __shared__ float sv[CAP2];
    __shared__ int   si[CAP2];
    __shared__ unsigned offs[G + 1];
    __shared__ int s_thr;
    __shared__ unsigned s_cnt;
    __shared__ float ovv[K];
    __shared__ int   ovi[K];

    const int tid = threadIdx.x;

    if (tid == 0) {
        unsigned o = 0;
        #pragma unroll
        for (int g2 = 0; g2 < G; ++g2) {
            offs[g2] = o;
            unsigned c = cnt2[bw * G + g2];
            o += (c < (unsigned)cap) ? c : (unsigned)cap;
        }
        offs[G] = o;
        s_cnt = 0u;
    }
    for (int i = tid; i < NBINS; i += 1024) hist[i] = 0u;
    __syncthreads();

    // gather candidates from the G private regions into LDS + histogram
    #pragma unroll
    for (int g2 = 0; g2 < G; ++g2) {
        const int o0 = (int)offs[g2];
        const int cg = (int)offs[g2 + 1] - o0;
        const size_t base = (size_t)(bw * G + g2) * (size_t)cap;
        for (int i = tid; i < cg; i += 1024) {
            const int dst = o0 + i;
            if (dst < CAPM) {
                float x = gv[base + i];
                cv[dst] = x;
                ci[dst] = gi[base + i];
                atomicAdd(&hist[okey(x) >> 20], 1u);
            }
        }
    }
    __syncthreads();

    // suffix scan: 4 bins per thread
    unsigned h[4];
    unsigned s = 0;
    #pragma unroll
    for (int k = 0; k < 4; ++k) { h[k] = hist[tid * 4 + k]; s += h[k]; }
    tsum[tid] = s;
    __syncthreads();
    for (int off = 1; off < 1024; off <<= 1) {
        unsigned add = (tid + off < 1024) ? tsum[tid + off] : 0u;
        __syncthreads();
        tsum[tid] += add;
        __syncthreads();
    }
    unsigned sfx = (tid == 1023) ? 0u : tsum[tid + 1];
    #pragma unroll
    for (int k = 3; k >= 0; --k) {
        unsigned nxt = sfx;
        sfx += h[k];
        if (sfx >= (unsigned)K && nxt < (unsigned)K) s_thr = tid * 4 + k;
    }
    __syncthreads();

    const int cnt = (int)((offs[G] < (unsigned)CAPM) ? offs[G] : (unsigned)CAPM);
    const unsigned thr = (unsigned)s_thr;
    for (int i = tid; i < cnt; i += 1024) {
        if ((okey(cv[i]) >> 20) >= thr) {
            unsigned p = atomicAdd(&s_cnt, 1u);
            if (p < CAP2) { sv[p] = cv[i]; si[p] = ci[i]; }
        }
    }
    __syncthreads();

    // exact rank (desc value, asc index)
    const int c2 = (int)((s_cnt < (unsigned)CAP2) ? s_cnt : (unsigned)CAP2);
    for (int i = tid; i < c2; i += 1024) {
        const float vi = sv[i];
        const int ii = si[i];
        int r = 0;
        for (int j = 0; j < c2; ++j) {
            const float vj = sv[j];
            r += (vj > vi || (vj == vi && si[j] < ii)) ? 1 : 0;
        }
        if (r < K) { ovv[r] = vi; ovi[r] = ii; }
    }
    __syncthreads();

    // finalize epilogue for this branch
    if (tid < K) {
        const float Himg = tsz[b * 2 + 0];
        const float Wimg = tsz[b * 2 + 1];
        const float vlog = ovv[tid];
        const int idx = ovi[tid];
        const float sp = sigm(vlog);
        const int q = idx / NC;
        const int lab = idx - q * NC;
        if (which == 0) {
            const int keep = sp > 0.3f ? 1 : 0;
            out[O_V + b * K + tid] = sp;
            out[O_LAB + b * K + tid] = keep ? (float)lab : -1.f;
            const float* pb = boxes_in + ((size_t)b * Q + q) * 4;
            const float cx = pb[0], cy = pb[1], w = pb[2], hh = pb[3];
            float* ob = out + O_BOX + ((size_t)b * K + tid) * 4;
            ob[0] = (cx - 0.5f * w) * Wimg;
            ob[1] = (cy - 0.5f * hh) * Himg;
            ob[2] = (cx + 0.5f * w) * Wimg;
            ob[3] = (cy + 0.5f * hh) * Himg;
            out[O_KEEP + b * K + tid] = keep ? 1.f : 0.f;
            ws_keep[b * K + tid] = keep;
            ws_q[b * K + tid] = q;
        } else {
            out[O_VG + b * K + tid] = sp;
            out[O_LABG + b * K + tid] = (float)lab;
            const float* pg = boxes_g_in + ((size_t)b * Q + q) * 4;
            float* obg = out + O_BG + ((size_t)b * K + tid) * 5;
            obg[0] = pg[0] * Wimg;
            obg[1] = pg[1] * Himg;
            obg[2] = pg[2] * Wimg;
            obg[3] = pg[3] * Himg;
            const float* pa = angles_in + ((size_t)b * Q + q) * NA;
            int am = 0;
            float bv = pa[0];
            #pragma unroll
            for (int a = 1; a < NA; ++a) {
                const float x = pa[a];
                if (x > bv) { bv = x; am = a; }
            }
            obg[4] = (float)((am - 8) * 10 - 5);
        }
    }
}

// ---------------- adjacency gather ----------------
__global__ void adj_kernel(const float* __restrict__ adj_in,
                           const int* __restrict__ ws_keep,
                           const int* __restrict__ ws_q,
                           float* __restrict__ out) {
    const int bi = blockIdx.x;         // b*K + i
    const int b = bi / K;
    const int i = bi - b * K;
    const int j = threadIdx.x;
    if (j >= K) return;
    const int qi = ws_q[b * K + i];
    const int ki = ws_keep[b * K + i];
    const int qj = ws_q[b * K + j];
    const int kj = ws_keep[b * K + j];
    float val = 0.f;
    if (ki & kj) {
        const float a = adj_in[((size_t)b * Q + qi) * Q + qj];
        val = sigm(a);
    }
    out[O_ADJ + (size_t)bi * K + j] = val;
}

extern "C" void kernel_launch(void* const* d_in, const int* in_sizes, int n_in,
                              void* d_out, int out_size, void* d_ws, size_t ws_size,
                              hipStream_t stream) {
    const float* pred_logits   = (const float*)d_in[0];
    const float* pred_boxes    = (const float*)d_in[1];
    const float* pred_adj      = (const float*)d_in[2];
    const float* pred_logits_g = (const float*)d_in[3];
    const float* pred_angles_g = (const float*)d_in[4];
    const float* pred_boxes_g  = (const float*)d_in[5];
    const float* tsz           = (const float*)d_in[6];
    float* out = (float*)d_out;

    // ws layout (4-byte units): keep[3200] | q[3200] | cnt2[512] | gv[64*G*cap] | gi[64*G*cap]
    int* ws_keep = (int*)d_ws;
    int* ws_q    = ws_keep + 3200;
    unsigned* cnt2 = (unsigned*)(ws_q + 3200);
    size_t fixed = 3200 + 3200 + 512;
    size_t avail = ws_size / 4 > fixed ? ws_size / 4 - fixed : 0;
    int cap = (int)((avail / (64 * G * 2)) < 4096 ? (avail / (64 * G * 2)) : 4096);
    if (cap < 128) cap = 128;   // ws is ~2GB in practice; this path never triggers
    float* gv = (float*)(cnt2 + 512);
    int*   gi = (int*)(gv + (size_t)64 * G * cap);

    hipLaunchKernelGGL(topk_part, dim3(G, 64), dim3(BLK1), 0, stream,
                       pred_logits, pred_logits_g, cnt2, gv, gi, cap);
    hipLaunchKernelGGL(topk_merge, dim3(64), dim3(1024), 0, stream,
                       cnt2, gv, gi, pred_boxes, pred_boxes_g, pred_angles_g,
                       tsz, out, ws_keep, ws_q, cap);
    hipLaunchKernelGGL(adj_kernel, dim3(BB * K), dim3(128), 0, stream,
                       pred_adj, ws_keep, ws_q, out);
}